// Round 9
// baseline (563.333 us; speedup 1.0000x reference)
//
#include <hip/hip_runtime.h>

#define EMBED 1024
#define HEADS 16
#define HDIM 64
#define SEQ 2048
#define NBATCH 4
#define KVSTRIDE 136  // 68 bf16: 34 dwords = 2 mod 32 banks -> <=2-way col reads
#define VOFF (64 * KVSTRIDE)
#define NT (SEQ / 64)

typedef __bf16 bf16;
typedef __bf16 b8v __attribute__((ext_vector_type(8)));
typedef __bf16 b4v __attribute__((ext_vector_type(4)));
typedef float f4v __attribute__((ext_vector_type(4)));
typedef float f16v __attribute__((ext_vector_type(16)));
typedef unsigned long long u64;

#define QSCALE 0.045084220027780106f  // log2(e) / sqrt(EMBED)

static __device__ __forceinline__ f16v mfma32(b8v a, b8v b, f16v c) {
  return __builtin_amdgcn_mfma_f32_32x32x16_bf16(a, b, c, 0, 0, 0);
}

static __device__ __forceinline__ b8v lds_b8(const char* p) {
  const b4v lo = *reinterpret_cast<const b4v*>(p);
  const b4v h4 = *reinterpret_cast<const b4v*>(p + 8);
  b8v r;
#pragma unroll
  for (int j = 0; j < 4; ++j) { r[j] = lo[j]; r[4 + j] = h4[j]; }
  return r;
}

// ---------------------------------------------------------------------------
// Kernel 1 (unchanged from R6): fused Q/K/V projection + Wo cvt. grid=(1024,4).
// ---------------------------------------------------------------------------
__global__ __launch_bounds__(256) void proj_kernel(
    const float* __restrict__ q_in, const float* __restrict__ k_in,
    const float* __restrict__ v_in, const float* __restrict__ Wq,
    const float* __restrict__ Wk, const float* __restrict__ Wv,
    const float* __restrict__ Wo, bf16* __restrict__ Qp,
    bf16* __restrict__ Kp, bf16* __restrict__ VpT, bf16* __restrict__ Wb) {
  const int mode = blockIdx.y;
  const int tid = threadIdx.x;

  if (mode == 3) {
    const int i = (blockIdx.x * 256 + tid) * 4;
    const f4v v = *reinterpret_cast<const f4v*>(Wo + i);
    b4v o;
    o[0] = (bf16)v[0]; o[1] = (bf16)v[1]; o[2] = (bf16)v[2]; o[3] = (bf16)v[3];
    *reinterpret_cast<b4v*>(Wb + i) = o;
    return;
  }

  __shared__ __align__(16) char xl[128 * KVSTRIDE];
  __shared__ __align__(16) char wl[64 * KVSTRIDE];
  __shared__ __align__(16) char ol[128 * KVSTRIDE];  // mode2 uses [64][264B]

  const float* x = (mode == 0) ? q_in : (mode == 1) ? k_in : v_in;
  const float* W = (mode == 0) ? Wq : (mode == 1) ? Wk : Wv;
  const float wscale = (mode == 0) ? QSCALE : 1.0f;

  const int lane = tid & 63, wave = tid >> 6;
  const int l31 = lane & 31, hi = lane >> 5;
  const int bid = blockIdx.x;
  const int stile = bid & 15, nh = bid >> 4;
  const int n = nh >> 4, h = nh & 15;
  const int s0 = stile * 128;

  const float* xb = x + (size_t)(n * SEQ + s0) * EMBED + h * HDIM;
#pragma unroll
  for (int r = 0; r < 8; ++r) {
    const int idx = r * 256 + tid;
    const int row = idx >> 4, c = idx & 15;
    const f4v v = *reinterpret_cast<const f4v*>(xb + (size_t)row * EMBED + c * 4);
    b4v o;
    o[0] = (bf16)v[0]; o[1] = (bf16)v[1]; o[2] = (bf16)v[2]; o[3] = (bf16)v[3];
    *reinterpret_cast<b4v*>(xl + row * KVSTRIDE + c * 8) = o;
  }
#pragma unroll
  for (int r = 0; r < 4; ++r) {
    const int idx = r * 256 + tid;
    const int row = idx >> 4, c = idx & 15;
    const f4v v = *reinterpret_cast<const f4v*>(W + row * 64 + c * 4);
    b4v o;
    o[0] = (bf16)(v[0] * wscale); o[1] = (bf16)(v[1] * wscale);
    o[2] = (bf16)(v[2] * wscale); o[3] = (bf16)(v[3] * wscale);
    *reinterpret_cast<b4v*>(wl + row * KVSTRIDE + c * 8) = o;
  }
  __syncthreads();

  const int s0w = wave * 32;
  b8v wf[2][4], xf[4];
#pragma unroll
  for (int eb = 0; eb < 2; ++eb)
#pragma unroll
    for (int dk = 0; dk < 4; ++dk)
      wf[eb][dk] = lds_b8(wl + (eb * 32 + l31) * KVSTRIDE + dk * 32 + hi * 16);
#pragma unroll
  for (int dk = 0; dk < 4; ++dk)
    xf[dk] = lds_b8(xl + (s0w + l31) * KVSTRIDE + dk * 32 + hi * 16);

  if (mode < 2) {
#pragma unroll
    for (int eb = 0; eb < 2; ++eb) {
      f16v d;
#pragma unroll
      for (int i = 0; i < 16; ++i) d[i] = 0.f;
#pragma unroll
      for (int dk = 0; dk < 4; ++dk) d = mfma32(wf[eb][dk], xf[dk], d);
      char* orow = ol + (s0w + l31) * KVSTRIDE + eb * 64 + hi * 8;
#pragma unroll
      for (int qd = 0; qd < 4; ++qd) {
        b4v o;
#pragma unroll
        for (int rr = 0; rr < 4; ++rr) o[rr] = (bf16)d[qd * 4 + rr];
        *reinterpret_cast<b4v*>(orow + qd * 16) = o;
      }
    }
  } else {
#pragma unroll
    for (int eb = 0; eb < 2; ++eb) {
      f16v d;
#pragma unroll
      for (int i = 0; i < 16; ++i) d[i] = 0.f;
#pragma unroll
      for (int dk = 0; dk < 4; ++dk) d = mfma32(xf[dk], wf[eb][dk], d);
      char* orow = ol + (eb * 32 + l31) * 264 + s0w * 2 + hi * 8;
#pragma unroll
      for (int qd = 0; qd < 4; ++qd) {
        b4v o;
#pragma unroll
        for (int rr = 0; rr < 4; ++rr) o[rr] = (bf16)d[qd * 4 + rr];
        *reinterpret_cast<b4v*>(orow + qd * 16) = o;
      }
    }
  }
  __syncthreads();

  if (mode < 2) {
    bf16* outb = ((mode == 0) ? Qp : Kp) + (size_t)nh * SEQ * HDIM +
                 (size_t)s0 * HDIM;
#pragma unroll
    for (int r = 0; r < 4; ++r) {
      const int idx = r * 256 + tid;
      const int row = idx >> 3, c8 = idx & 7;
      const u64 a = *reinterpret_cast<const u64*>(ol + row * KVSTRIDE + c8 * 16);
      const u64 b = *reinterpret_cast<const u64*>(ol + row * KVSTRIDE + c8 * 16 + 8);
      uint4 v;
      v.x = (unsigned)a; v.y = (unsigned)(a >> 32);
      v.z = (unsigned)b; v.w = (unsigned)(b >> 32);
      *reinterpret_cast<uint4*>(outb + (size_t)row * HDIM + c8 * 8) = v;
    }
  } else {
    bf16* outb = VpT + (size_t)nh * HDIM * SEQ + s0;
#pragma unroll
    for (int r = 0; r < 4; ++r) {
      const int idx = r * 256 + tid;
      const int row = idx >> 4, c = idx & 15;
      const u64 a = *reinterpret_cast<const u64*>(ol + row * 264 + c * 16);
      const u64 b = *reinterpret_cast<const u64*>(ol + row * 264 + c * 16 + 8);
      uint4 v;
      v.x = (unsigned)a; v.y = (unsigned)(a >> 32);
      v.z = (unsigned)b; v.w = (unsigned)(b >> 32);
      *reinterpret_cast<uint4*>(outb + (size_t)row * SEQ + c * 8) = v;
    }
  }
}

// ---------------------------------------------------------------------------
// Kernel 2 (v7): R8's pipelined flash attn + (a) zero-const MFMA C operand
// (no per-iter S zero-init movs), (b) static 6-phase unroll (buffer rotation
// period 3 x pa ping-pong period 2) -> compile-time LDS bases, no pa copies.
// ---------------------------------------------------------------------------
__global__ __launch_bounds__(256, 2) void attn_kernel(
    const bf16* __restrict__ Qp, const bf16* __restrict__ Kp,
    const bf16* __restrict__ VpT, bf16* __restrict__ O) {
  __shared__ __align__(16) char smem[3][2 * 64 * KVSTRIDE];  // [buf][K | V]

  const int tid = threadIdx.x;
  const int lane = tid & 63, wave = tid >> 6;
  const int l31 = lane & 31, hi = lane >> 5;

  const int bid = blockIdx.x;
  const int nh = bid & 63, qb = bid >> 6;  // nh-major -> per-head XCD locality
  const int n = nh >> 4, h = nh & 15;
  const int q0 = qb * 256 + wave * 64;

  const bf16* Qnh = Qp + (size_t)nh * SEQ * HDIM;
  const bf16* Knh = Kp + (size_t)nh * SEQ * HDIM;
  const bf16* Vnh = VpT + (size_t)nh * HDIM * SEQ;

  // Q B-fragments (q = q0 + qt*32 + l31), pre-scaled by log2e/32.
  b8v bq[2][4];
#pragma unroll
  for (int qt = 0; qt < 2; ++qt)
#pragma unroll
    for (int dk = 0; dk < 4; ++dk)
      bq[qt][dk] = *reinterpret_cast<const b8v*>(
          Qnh + (size_t)(q0 + qt * 32 + l31) * HDIM + dk * 16 + hi * 8);

  f16v ZERO;
#pragma unroll
  for (int i = 0; i < 16; ++i) ZERO[i] = 0.f;

  f16v acc[2][2];
#pragma unroll
  for (int qt = 0; qt < 2; ++qt)
#pragma unroll
    for (int dblk = 0; dblk < 2; ++dblk) acc[qt][dblk] = ZERO;
  float lsum0 = 0.f, lsum1 = 0.f;

  const int srow = tid >> 3, seg = tid & 7;
  uint4 kst[2], vst[2];

#define G_ISSUE(kv0)                                                           \
  {                                                                            \
    kst[0] = *reinterpret_cast<const uint4*>(Knh + (size_t)((kv0) + srow) * HDIM + seg * 8); \
    kst[1] = *reinterpret_cast<const uint4*>(Knh + (size_t)((kv0) + srow + 32) * HDIM + seg * 8); \
    vst[0] = *reinterpret_cast<const uint4*>(Vnh + (size_t)srow * SEQ + (kv0) + seg * 8); \
    vst[1] = *reinterpret_cast<const uint4*>(Vnh + (size_t)(srow + 32) * SEQ + (kv0) + seg * 8); \
  }

#define L_WRITE(base)                                                          \
  {                                                                            \
    _Pragma("unroll")                                                          \
    for (int rr = 0; rr < 2; ++rr) {                                           \
      char* kd = (base) + (srow + 32 * rr) * KVSTRIDE + seg * 16;              \
      const u64* kp = reinterpret_cast<const u64*>(&kst[rr]);                  \
      *reinterpret_cast<u64*>(kd) = kp[0];                                     \
      *reinterpret_cast<u64*>(kd + 8) = kp[1];                                 \
      char* vd = (base) + VOFF + (srow + 32 * rr) * KVSTRIDE + seg * 16;       \
      const u64* vp = reinterpret_cast<const u64*>(&vst[rr]);                  \
      *reinterpret_cast<u64*>(vd) = vp[0];                                     \
      *reinterpret_cast<u64*>(vd + 8) = vp[1];                                 \
    }                                                                          \
  }

// QK of one tile from K at kbase -> s[2][2]; first dk uses ZERO as C operand
#define QK_TILE(kbase, s)                                                      \
  {                                                                            \
    _Pragma("unroll")                                                          \
    for (int g = 0; g < 2; ++g) {                                              \
      const char* kr = (kbase) + (g * 32 + l31) * KVSTRIDE + hi * 16;          \
      const b8v ak0 = lds_b8(kr);                                              \
      s[0][g] = mfma32(ak0, bq[0][0], ZERO);                                   \
      s[1][g] = mfma32(ak0, bq[1][0], ZERO);                                   \
      _Pragma("unroll")                                                        \
      for (int dk = 1; dk < 4; ++dk) {                                         \
        const b8v ak = lds_b8(kr + dk * 32);                                   \
        s[0][g] = mfma32(ak, bq[0][dk], s[0][g]);                              \
        s[1][g] = mfma32(ak, bq[1][dk], s[1][g]);                              \
      }                                                                        \
    }                                                                          \
  }

#define EXP_QT(sg0, sg1, pa, psum)                                             \
  {                                                                            \
    _Pragma("unroll")                                                          \
    for (int reg = 0; reg < 16; ++reg) {                                       \
      const float p0 = __builtin_amdgcn_exp2f(sg0[reg]);                       \
      const float p1 = __builtin_amdgcn_exp2f(sg1[reg]);                       \
      psum += p0 + p1;                                                         \
      pa[0][reg >> 3][reg & 7] = (bf16)p0;                                     \
      pa[1][reg >> 3][reg & 7] = (bf16)p1;                                     \
    }                                                                          \
  }

#define PV_DBLK(vbase, dblk, paA, paB)                                         \
  {                                                                            \
    const char* vr = (vbase) + VOFF + ((dblk) * 32 + l31) * KVSTRIDE + hi * 8; \
    _Pragma("unroll")                                                          \
    for (int g = 0; g < 2; ++g) {                                              \
      _Pragma("unroll")                                                        \
      for (int kc = 0; kc < 2; ++kc) {                                         \
        const b4v lo = *reinterpret_cast<const b4v*>(vr + g * 64 + kc * 32);   \
        const b4v h4 = *reinterpret_cast<const b4v*>(vr + g * 64 + kc * 32 + 16); \
        b8v bv;                                                                \
        _Pragma("unroll")                                                      \
        for (int j = 0; j < 4; ++j) { bv[j] = lo[j]; bv[4 + j] = h4[j]; }      \
        acc[0][dblk] = mfma32(paA[g][kc], bv, acc[0][dblk]);                   \
        acc[1][dblk] = mfma32(paB[g][kc], bv, acc[1][dblk]);                   \
      }                                                                        \
    }                                                                          \
  }

// One pipeline step at tile t: QK(t+1) from BN, PV(t) from BC with PAC,
// softmax(t+1) -> PAN, stage(t+2) -> BF, barrier.
#define ITER(PAC, PAN, BC, BN, BF)                                             \
  {                                                                            \
    G_ISSUE((t + 2) * 64);                                                     \
    f16v s[2][2];                                                              \
    __builtin_amdgcn_s_setprio(1);                                             \
    QK_TILE(BN, s);                                                            \
    __builtin_amdgcn_s_setprio(0);                                             \
    float ps0 = 0.f, ps1 = 0.f;                                                \
    PV_DBLK(BC, 0, PAC[0], PAC[1]);                                            \
    EXP_QT(s[0][0], s[0][1], PAN[0], ps0);                                     \
    PV_DBLK(BC, 1, PAC[0], PAC[1]);                                            \
    EXP_QT(s[1][0], s[1][1], PAN[1], ps1);                                     \
    lsum0 += ps0;                                                              \
    lsum1 += ps1;                                                              \
    L_WRITE(BF);                                                               \
    __syncthreads();                                                           \
    ++t;                                                                       \
  }

  // ---- prologue: stage tiles 0,1; QK(0)+softmax(0) -> paA ----
  G_ISSUE(0);
  L_WRITE(smem[0]);
  G_ISSUE(64);
  L_WRITE(smem[1]);
  __syncthreads();

  b8v paA[2][2][2], paB[2][2][2];  // ping-pong P fragments
  {
    f16v s[2][2];
    QK_TILE(smem[0], s);
    float ps0 = 0.f, ps1 = 0.f;
    EXP_QT(s[0][0], s[0][1], paA[0], ps0);
    EXP_QT(s[1][0], s[1][1], paA[1], ps1);
    lsum0 += ps0;
    lsum1 += ps1;
  }

  // ---- main loop: 30 iters as 5 x 6-phase static unroll, then 1 more ----
  int t = 0;
  for (int p = 0; p < 5; ++p) {
    ITER(paA, paB, smem[0], smem[1], smem[2]);
    ITER(paB, paA, smem[1], smem[2], smem[0]);
    ITER(paA, paB, smem[2], smem[0], smem[1]);
    ITER(paB, paA, smem[0], smem[1], smem[2]);
    ITER(paA, paB, smem[1], smem[2], smem[0]);
    ITER(paB, paA, smem[2], smem[0], smem[1]);
  }
  // t = 30: last pipelined iter (no stage of t+2 = 32)
  {
    f16v s[2][2];
    __builtin_amdgcn_s_setprio(1);
    QK_TILE(smem[1], s);
    __builtin_amdgcn_s_setprio(0);
    float ps0 = 0.f, ps1 = 0.f;
    PV_DBLK(smem[0], 0, paA[0], paA[1]);
    EXP_QT(s[0][0], s[0][1], paB[0], ps0);
    PV_DBLK(smem[0], 1, paA[0], paA[1]);
    EXP_QT(s[1][0], s[1][1], paB[1], ps1);
    lsum0 += ps0;
    lsum1 += ps1;
  }

  // ---- epilogue: PV(31) from smem[1] with paB ----
  __builtin_amdgcn_s_setprio(1);
  PV_DBLK(smem[1], 0, paB[0], paB[1]);
  PV_DBLK(smem[1], 1, paB[0], paB[1]);
  __builtin_amdgcn_s_setprio(0);

  lsum0 += __shfl_xor(lsum0, 32);
  lsum1 += __shfl_xor(lsum1, 32);

#pragma unroll
  for (int qt = 0; qt < 2; ++qt) {
    const float ls = (qt == 0) ? lsum0 : lsum1;
#pragma unroll
    for (int reg = 0; reg < 16; ++reg) {
      const int qrow = (reg & 3) + 8 * (reg >> 2) + 4 * hi;
      const float rinv = __builtin_amdgcn_rcpf(__shfl(ls, qrow, 64));
#pragma unroll
      for (int dblk = 0; dblk < 2; ++dblk) {
        O[(size_t)(n * SEQ + q0 + qt * 32 + qrow) * EMBED + h * HDIM +
          dblk * 32 + l31] = (bf16)(acc[qt][dblk][reg] * rinv);
      }
    }
  }
#undef G_ISSUE
#undef L_WRITE
#undef QK_TILE
#undef EXP_QT
#undef PV_DBLK
#undef ITER
}

// ---------------------------------------------------------------------------
// Kernel 4 (unchanged from R7): LDS-staged out_gemm.
// ---------------------------------------------------------------------------
__global__ __launch_bounds__(256) void out_gemm(
    const bf16* __restrict__ O, const bf16* __restrict__ Wb,
    const float* __restrict__ bo, float* __restrict__ Y) {
  __shared__ __align__(16) char smem[2][2][128 * KVSTRIDE];

  const int tid = threadIdx.x;
  const int lane = tid & 63, wave = tid >> 6;
  const int l31 = lane & 31, hi = lane >> 5;
  const int m0 = blockIdx.x * 128;
  const int j0 = blockIdx.y * 128;
  const int mw = (wave >> 1) * 64, jw = (wave & 1) * 64;

  f16v acc[2][2];
#pragma unroll
  for (int mt = 0; mt < 2; ++mt)
#pragma unroll
    for (int jt = 0; jt < 2; ++jt)
#pragma unroll
      for (int i = 0; i < 16; ++i) acc[mt][jt][i] = 0.f;

  const bf16* Ab = O + (size_t)m0 * EMBED;
  const bf16* Bb = Wb + (size_t)j0 * EMBED;
  const int srow = tid >> 3, seg = tid & 7;
  uint4 ast[4], bst[4];

#define G_ISSUE(kt)                                                            \
  {                                                                            \
    _Pragma("unroll")                                                          \
    for (int rr = 0; rr < 4; ++rr) {                                           \
      ast[rr] = *reinterpret_cast<const uint4*>(                               \
          Ab + (size_t)(srow + 32 * rr) * EMBED + (kt) * 64 + seg * 8);        \
      bst[rr] = *reinterpret_cast<const uint4*>(                               \
          Bb + (size_t)(srow + 32 * rr) * EMBED + (kt) * 64 + seg * 8);        \
    }                                                                          \
  }

#define L_WRITE(c)                                                             \
  {                                                                            \
    _Pragma("unroll")                                                          \
    for (int rr = 0; rr < 4; ++rr) {                                           \
      char* ad = &smem[c][0][(srow + 32 * rr) * KVSTRIDE + seg * 16];          \
      const u64* ap = reinterpret_cast<const u64*>(&ast[rr]);                  \
      *reinterpret_cast<u64*>(ad) = ap[0];                                     \
      *reinterpret_cast<u64*>(ad + 8) = ap[1];                                 \
      char* bd = &smem[c][1][(srow + 32 * rr) * KVSTRIDE + seg * 16];          \
      const u64* bp = reinterpret_cast<const u64*>(&bst[rr]);                  \
      *reinterpret_cast<u64*>(bd) = bp[0];                                     \
      *reinterpret_cast<u64*>(bd + 8) = bp[1];                                 \
    }                                                                          \
  }

  G_ISSUE(0);
  L_WRITE(0);
  __syncthreads();
  int cur = 0;

  for (int kt = 0; kt < EMBED / 64; ++kt) {
    if (kt + 1 < EMBED / 64) G_ISSUE(kt + 1);

    const char* at = smem[cur][0];
    const char* bt = smem[cur][1];

    __builtin_amdgcn_s_setprio(1);
#pragma unroll
    for (int dk = 0; dk < 4; ++dk) {
      b8v a[2], b[2];
#pragma unroll
      for (int mt = 0; mt < 2; ++mt)
        a[mt] = lds_b8(at + (mw + mt * 32 + l31) * KVSTRIDE + dk * 32 + hi * 16);
#pragma unroll
      for (int jt = 0; jt < 2; ++jt)
        b[jt] = lds_b8(bt + (jw + jt * 32 + l31) * KVSTRIDE + dk * 32 + hi * 16);
      acc[0][0] = mfma32(a[0], b[0], acc[0][0]);
      acc[0][1] = mfma32(a[0], b[1], acc[0][1]);
      acc[1][0] = mfma32(a[1], b[0], acc[1][0]);
      acc[1][1] = mfma32(a[1], b[1], acc[1][1]);
    }
    __builtin_amdgcn_s_setprio(0);

    if (kt + 1 < EMBED / 64) L_WRITE(cur ^ 1);
    __syncthreads();
    cur ^= 1;
  }

#pragma unroll
  for (int jt = 0; jt < 2; ++jt) {
    const float bias = bo[j0 + jw + jt * 32 + l31];
#pragma unroll
    for (int mt = 0; mt < 2; ++mt)
#pragma unroll
      for (int reg = 0; reg < 16; ++reg) {
        const int mrow = (reg & 3) + 8 * (reg >> 2) + 4 * hi;
        Y[(size_t)(m0 + mw + mt * 32 + mrow) * EMBED + j0 + jw + jt * 32 + l31] =
            acc[mt][jt][reg] + bias;
      }
  }
#undef G_ISSUE
#undef L_WRITE
}

// ---------------------------------------------------------------------------
extern "C" void kernel_launch(void* const* d_in, const int* in_sizes, int n_in,
                              void* d_out, int out_size, void* d_ws, size_t ws_size,
                              hipStream_t stream) {
  const float* query  = (const float*)d_in[0];
  const float* keys   = (const float*)d_in[1];
  const float* values = (const float*)d_in[2];
  const float* Wq = (const float*)d_in[3];
  const float* Wk = (const float*)d_in[4];
  const float* Wv = (const float*)d_in[5];
  const float* Wo = (const float*)d_in[6];
  const float* bo = (const float*)d_in[7];
  float* Y = (float*)d_out;

  char* ws = (char*)d_ws;
  const size_t szP = (size_t)NBATCH * HEADS * SEQ * HDIM * sizeof(bf16);  // 16.78 MB
  bf16* Qp  = (bf16*)(ws);
  bf16* Kp  = (bf16*)(ws + szP);
  bf16* VpT = (bf16*)(ws + 2 * szP);
  bf16* O   = (bf16*)(ws + 3 * szP);
  bf16* Wb  = (bf16*)(ws + 4 * szP);

  proj_kernel<<<dim3(1024, 4), dim3(256), 0, stream>>>(
      query, keys, values, Wq, Wk, Wv, Wo, Qp, Kp, VpT, Wb);
  attn_kernel<<<dim3(512), dim3(256), 0, stream>>>(Qp, Kp, VpT, O);
  out_gemm<<<dim3(64, 8), dim3(256), 0, stream>>>(O, Wb, bo, Y);
}

// Round 10
// 174.395 us; speedup vs baseline: 3.2302x; 3.2302x over previous
//
#include <hip/hip_runtime.h>

#define EMBED 1024
#define HEADS 16
#define HDIM 64
#define SEQ 2048
#define NBATCH 4
#define KVSTRIDE 136  // 68 bf16: 34 dwords = 2 mod 32 banks -> <=2-way col reads
#define VOFF (64 * KVSTRIDE)
#define NT (SEQ / 64)

typedef __bf16 bf16;
typedef __bf16 b8v __attribute__((ext_vector_type(8)));
typedef __bf16 b4v __attribute__((ext_vector_type(4)));
typedef float f4v __attribute__((ext_vector_type(4)));
typedef float f16v __attribute__((ext_vector_type(16)));
typedef unsigned long long u64;

#define QSCALE 0.045084220027780106f  // log2(e) / sqrt(EMBED)

static __device__ __forceinline__ f16v mfma32(b8v a, b8v b, f16v c) {
  return __builtin_amdgcn_mfma_f32_32x32x16_bf16(a, b, c, 0, 0, 0);
}

static __device__ __forceinline__ b8v lds_b8(const char* p) {
  const b4v lo = *reinterpret_cast<const b4v*>(p);
  const b4v h4 = *reinterpret_cast<const b4v*>(p + 8);
  b8v r;
#pragma unroll
  for (int j = 0; j < 4; ++j) { r[j] = lo[j]; r[4 + j] = h4[j]; }
  return r;
}

// ---------------------------------------------------------------------------
// Kernel 1 (unchanged from R6): fused Q/K/V projection + Wo cvt. grid=(1024,4).
// ---------------------------------------------------------------------------
__global__ __launch_bounds__(256) void proj_kernel(
    const float* __restrict__ q_in, const float* __restrict__ k_in,
    const float* __restrict__ v_in, const float* __restrict__ Wq,
    const float* __restrict__ Wk, const float* __restrict__ Wv,
    const float* __restrict__ Wo, bf16* __restrict__ Qp,
    bf16* __restrict__ Kp, bf16* __restrict__ VpT, bf16* __restrict__ Wb) {
  const int mode = blockIdx.y;
  const int tid = threadIdx.x;

  if (mode == 3) {
    const int i = (blockIdx.x * 256 + tid) * 4;
    const f4v v = *reinterpret_cast<const f4v*>(Wo + i);
    b4v o;
    o[0] = (bf16)v[0]; o[1] = (bf16)v[1]; o[2] = (bf16)v[2]; o[3] = (bf16)v[3];
    *reinterpret_cast<b4v*>(Wb + i) = o;
    return;
  }

  __shared__ __align__(16) char xl[128 * KVSTRIDE];
  __shared__ __align__(16) char wl[64 * KVSTRIDE];
  __shared__ __align__(16) char ol[128 * KVSTRIDE];  // mode2 uses [64][264B]

  const float* x = (mode == 0) ? q_in : (mode == 1) ? k_in : v_in;
  const float* W = (mode == 0) ? Wq : (mode == 1) ? Wk : Wv;
  const float wscale = (mode == 0) ? QSCALE : 1.0f;

  const int lane = tid & 63, wave = tid >> 6;
  const int l31 = lane & 31, hi = lane >> 5;
  const int bid = blockIdx.x;
  const int stile = bid & 15, nh = bid >> 4;
  const int n = nh >> 4, h = nh & 15;
  const int s0 = stile * 128;

  const float* xb = x + (size_t)(n * SEQ + s0) * EMBED + h * HDIM;
#pragma unroll
  for (int r = 0; r < 8; ++r) {
    const int idx = r * 256 + tid;
    const int row = idx >> 4, c = idx & 15;
    const f4v v = *reinterpret_cast<const f4v*>(xb + (size_t)row * EMBED + c * 4);
    b4v o;
    o[0] = (bf16)v[0]; o[1] = (bf16)v[1]; o[2] = (bf16)v[2]; o[3] = (bf16)v[3];
    *reinterpret_cast<b4v*>(xl + row * KVSTRIDE + c * 8) = o;
  }
#pragma unroll
  for (int r = 0; r < 4; ++r) {
    const int idx = r * 256 + tid;
    const int row = idx >> 4, c = idx & 15;
    const f4v v = *reinterpret_cast<const f4v*>(W + row * 64 + c * 4);
    b4v o;
    o[0] = (bf16)(v[0] * wscale); o[1] = (bf16)(v[1] * wscale);
    o[2] = (bf16)(v[2] * wscale); o[3] = (bf16)(v[3] * wscale);
    *reinterpret_cast<b4v*>(wl + row * KVSTRIDE + c * 8) = o;
  }
  __syncthreads();

  const int s0w = wave * 32;
  b8v wf[2][4], xf[4];
#pragma unroll
  for (int eb = 0; eb < 2; ++eb)
#pragma unroll
    for (int dk = 0; dk < 4; ++dk)
      wf[eb][dk] = lds_b8(wl + (eb * 32 + l31) * KVSTRIDE + dk * 32 + hi * 16);
#pragma unroll
  for (int dk = 0; dk < 4; ++dk)
    xf[dk] = lds_b8(xl + (s0w + l31) * KVSTRIDE + dk * 32 + hi * 16);

  if (mode < 2) {
#pragma unroll
    for (int eb = 0; eb < 2; ++eb) {
      f16v d;
#pragma unroll
      for (int i = 0; i < 16; ++i) d[i] = 0.f;
#pragma unroll
      for (int dk = 0; dk < 4; ++dk) d = mfma32(wf[eb][dk], xf[dk], d);
      char* orow = ol + (s0w + l31) * KVSTRIDE + eb * 64 + hi * 8;
#pragma unroll
      for (int qd = 0; qd < 4; ++qd) {
        b4v o;
#pragma unroll
        for (int rr = 0; rr < 4; ++rr) o[rr] = (bf16)d[qd * 4 + rr];
        *reinterpret_cast<b4v*>(orow + qd * 16) = o;
      }
    }
  } else {
#pragma unroll
    for (int eb = 0; eb < 2; ++eb) {
      f16v d;
#pragma unroll
      for (int i = 0; i < 16; ++i) d[i] = 0.f;
#pragma unroll
      for (int dk = 0; dk < 4; ++dk) d = mfma32(xf[dk], wf[eb][dk], d);
      char* orow = ol + (eb * 32 + l31) * 264 + s0w * 2 + hi * 8;
#pragma unroll
      for (int qd = 0; qd < 4; ++qd) {
        b4v o;
#pragma unroll
        for (int rr = 0; rr < 4; ++rr) o[rr] = (bf16)d[qd * 4 + rr];
        *reinterpret_cast<b4v*>(orow + qd * 16) = o;
      }
    }
  }
  __syncthreads();

  if (mode < 2) {
    bf16* outb = ((mode == 0) ? Qp : Kp) + (size_t)nh * SEQ * HDIM +
                 (size_t)s0 * HDIM;
#pragma unroll
    for (int r = 0; r < 4; ++r) {
      const int idx = r * 256 + tid;
      const int row = idx >> 3, c8 = idx & 7;
      const u64 a = *reinterpret_cast<const u64*>(ol + row * KVSTRIDE + c8 * 16);
      const u64 b = *reinterpret_cast<const u64*>(ol + row * KVSTRIDE + c8 * 16 + 8);
      uint4 v;
      v.x = (unsigned)a; v.y = (unsigned)(a >> 32);
      v.z = (unsigned)b; v.w = (unsigned)(b >> 32);
      *reinterpret_cast<uint4*>(outb + (size_t)row * HDIM + c8 * 8) = v;
    }
  } else {
    bf16* outb = VpT + (size_t)nh * HDIM * SEQ + s0;
#pragma unroll
    for (int r = 0; r < 4; ++r) {
      const int idx = r * 256 + tid;
      const int row = idx >> 4, c = idx & 15;
      const u64 a = *reinterpret_cast<const u64*>(ol + row * 264 + c * 16);
      const u64 b = *reinterpret_cast<const u64*>(ol + row * 264 + c * 16 + 8);
      uint4 v;
      v.x = (unsigned)a; v.y = (unsigned)(a >> 32);
      v.z = (unsigned)b; v.w = (unsigned)(b >> 32);
      *reinterpret_cast<uint4*>(outb + (size_t)row * SEQ + c * 8) = v;
    }
  }
}

// ---------------------------------------------------------------------------
// Kernel 2 (v8): R8's pipelined flash attn (runtime 3-buffer rotation, proven
// codegen) + ZERO-const MFMA C operand (no per-iter S zero-init) + 2-deep
// static unroll for the pa ping-pong only (no 32-mov handoff copy).
// ---------------------------------------------------------------------------
__global__ __launch_bounds__(256, 2) void attn_kernel(
    const bf16* __restrict__ Qp, const bf16* __restrict__ Kp,
    const bf16* __restrict__ VpT, bf16* __restrict__ O) {
  __shared__ __align__(16) char smem[3][2 * 64 * KVSTRIDE];  // [buf][K | V]

  const int tid = threadIdx.x;
  const int lane = tid & 63, wave = tid >> 6;
  const int l31 = lane & 31, hi = lane >> 5;

  const int bid = blockIdx.x;
  const int nh = bid & 63, qb = bid >> 6;  // nh-major -> per-head XCD locality
  const int n = nh >> 4, h = nh & 15;
  const int q0 = qb * 256 + wave * 64;

  const bf16* Qnh = Qp + (size_t)nh * SEQ * HDIM;
  const bf16* Knh = Kp + (size_t)nh * SEQ * HDIM;
  const bf16* Vnh = VpT + (size_t)nh * HDIM * SEQ;

  // Q B-fragments (q = q0 + qt*32 + l31), pre-scaled by log2e/32.
  b8v bq[2][4];
#pragma unroll
  for (int qt = 0; qt < 2; ++qt)
#pragma unroll
    for (int dk = 0; dk < 4; ++dk)
      bq[qt][dk] = *reinterpret_cast<const b8v*>(
          Qnh + (size_t)(q0 + qt * 32 + l31) * HDIM + dk * 16 + hi * 8);

  f16v ZERO;
#pragma unroll
  for (int i = 0; i < 16; ++i) ZERO[i] = 0.f;

  f16v acc[2][2];
#pragma unroll
  for (int qt = 0; qt < 2; ++qt)
#pragma unroll
    for (int dblk = 0; dblk < 2; ++dblk) acc[qt][dblk] = ZERO;
  float lsum0 = 0.f, lsum1 = 0.f;

  const int srow = tid >> 3, seg = tid & 7;
  uint4 kst[2], vst[2];

#define G_ISSUE(kv0)                                                           \
  {                                                                            \
    kst[0] = *reinterpret_cast<const uint4*>(Knh + (size_t)((kv0) + srow) * HDIM + seg * 8); \
    kst[1] = *reinterpret_cast<const uint4*>(Knh + (size_t)((kv0) + srow + 32) * HDIM + seg * 8); \
    vst[0] = *reinterpret_cast<const uint4*>(Vnh + (size_t)srow * SEQ + (kv0) + seg * 8); \
    vst[1] = *reinterpret_cast<const uint4*>(Vnh + (size_t)(srow + 32) * SEQ + (kv0) + seg * 8); \
  }

#define L_WRITE(base)                                                          \
  {                                                                            \
    _Pragma("unroll")                                                          \
    for (int rr = 0; rr < 2; ++rr) {                                           \
      char* kd = (base) + (srow + 32 * rr) * KVSTRIDE + seg * 16;              \
      const u64* kp = reinterpret_cast<const u64*>(&kst[rr]);                  \
      *reinterpret_cast<u64*>(kd) = kp[0];                                     \
      *reinterpret_cast<u64*>(kd + 8) = kp[1];                                 \
      char* vd = (base) + VOFF + (srow + 32 * rr) * KVSTRIDE + seg * 16;       \
      const u64* vp = reinterpret_cast<const u64*>(&vst[rr]);                  \
      *reinterpret_cast<u64*>(vd) = vp[0];                                     \
      *reinterpret_cast<u64*>(vd + 8) = vp[1];                                 \
    }                                                                          \
  }

// QK of one tile: first dk uses ZERO as the C operand (no zero-init movs)
#define QK_TILE(kbase, s)                                                      \
  {                                                                            \
    _Pragma("unroll")                                                          \
    for (int g = 0; g < 2; ++g) {                                              \
      const char* kr = (kbase) + (g * 32 + l31) * KVSTRIDE + hi * 16;          \
      const b8v ak0 = lds_b8(kr);                                              \
      s[0][g] = mfma32(ak0, bq[0][0], ZERO);                                   \
      s[1][g] = mfma32(ak0, bq[1][0], ZERO);                                   \
      _Pragma("unroll")                                                        \
      for (int dk = 1; dk < 4; ++dk) {                                         \
        const b8v ak = lds_b8(kr + dk * 32);                                   \
        s[0][g] = mfma32(ak, bq[0][dk], s[0][g]);                              \
        s[1][g] = mfma32(ak, bq[1][dk], s[1][g]);                              \
      }                                                                        \
    }                                                                          \
  }

#define EXP_QT(sg0, sg1, pa, psum)                                             \
  {                                                                            \
    _Pragma("unroll")                                                          \
    for (int reg = 0; reg < 16; ++reg) {                                       \
      const float p0 = __builtin_amdgcn_exp2f(sg0[reg]);                       \
      const float p1 = __builtin_amdgcn_exp2f(sg1[reg]);                       \
      psum += p0 + p1;                                                         \
      pa[0][reg >> 3][reg & 7] = (bf16)p0;                                     \
      pa[1][reg >> 3][reg & 7] = (bf16)p1;                                     \
    }                                                                          \
  }

#define PV_DBLK(vbase, dblk, paA_, paB_)                                       \
  {                                                                            \
    const char* vr = (vbase) + VOFF + ((dblk) * 32 + l31) * KVSTRIDE + hi * 8; \
    _Pragma("unroll")                                                          \
    for (int g = 0; g < 2; ++g) {                                              \
      _Pragma("unroll")                                                        \
      for (int kc = 0; kc < 2; ++kc) {                                         \
        const b4v lo = *reinterpret_cast<const b4v*>(vr + g * 64 + kc * 32);   \
        const b4v h4 = *reinterpret_cast<const b4v*>(vr + g * 64 + kc * 32 + 16); \
        b8v bv;                                                                \
        _Pragma("unroll")                                                      \
        for (int j = 0; j < 4; ++j) { bv[j] = lo[j]; bv[4 + j] = h4[j]; }      \
        acc[0][dblk] = mfma32(paA_[g][kc], bv, acc[0][dblk]);                  \
        acc[1][dblk] = mfma32(paB_[g][kc], bv, acc[1][dblk]);                  \
      }                                                                        \
    }                                                                          \
  }

// One pipeline step: QK(t+1) from pN, PV(t) from pC with PAC, softmax->PAN,
// stage(t+2)->pF, rotate pointers, barrier. Guarded for the tail.
#define ITER(PAC, PAN)                                                         \
  {                                                                            \
    const bool more = (t + 2 < NT);                                            \
    if (more) G_ISSUE((t + 2) * 64);                                           \
    f16v s[2][2];                                                              \
    __builtin_amdgcn_s_setprio(1);                                             \
    QK_TILE(pN, s);                                                            \
    __builtin_amdgcn_s_setprio(0);                                             \
    float ps0 = 0.f, ps1 = 0.f;                                                \
    PV_DBLK(pC, 0, PAC[0], PAC[1]);                                            \
    EXP_QT(s[0][0], s[0][1], PAN[0], ps0);                                     \
    PV_DBLK(pC, 1, PAC[0], PAC[1]);                                            \
    EXP_QT(s[1][0], s[1][1], PAN[1], ps1);                                     \
    lsum0 += ps0;                                                              \
    lsum1 += ps1;                                                              \
    if (more) L_WRITE(pF);                                                     \
    char* tmp_ = pC; pC = pN; pN = pF; pF = tmp_;                              \
    __syncthreads();                                                           \
    ++t;                                                                       \
  }

  // ---- prologue: stage tiles 0,1; QK(0)+softmax(0) -> paA ----
  G_ISSUE(0);
  L_WRITE(smem[0]);
  G_ISSUE(64);
  L_WRITE(smem[1]);
  __syncthreads();

  char* pC = smem[0];
  char* pN = smem[1];
  char* pF = smem[2];

  b8v paA[2][2][2], paB[2][2][2];  // ping-pong P fragments (static roles)
  {
    f16v s[2][2];
    QK_TILE(pC, s);
    float ps0 = 0.f, ps1 = 0.f;
    EXP_QT(s[0][0], s[0][1], paA[0], ps0);
    EXP_QT(s[1][0], s[1][1], paA[1], ps1);
    lsum0 += ps0;
    lsum1 += ps1;
  }

  // ---- main loop: 31 iters = 15 x (A->B, B->A) + final (A->B) ----
  int t = 0;
  for (int p = 0; p < 15; ++p) {
    ITER(paA, paB);
    ITER(paB, paA);
  }
  ITER(paA, paB);  // t = 30 (tail: no stage of tile 32)

  // ---- epilogue: PV(31); after rotation pC points at tile 31 ----
  __builtin_amdgcn_s_setprio(1);
  PV_DBLK(pC, 0, paB[0], paB[1]);
  PV_DBLK(pC, 1, paB[0], paB[1]);
  __builtin_amdgcn_s_setprio(0);

  lsum0 += __shfl_xor(lsum0, 32);
  lsum1 += __shfl_xor(lsum1, 32);

#pragma unroll
  for (int qt = 0; qt < 2; ++qt) {
    const float ls = (qt == 0) ? lsum0 : lsum1;
#pragma unroll
    for (int reg = 0; reg < 16; ++reg) {
      const int qrow = (reg & 3) + 8 * (reg >> 2) + 4 * hi;
      const float rinv = __builtin_amdgcn_rcpf(__shfl(ls, qrow, 64));
#pragma unroll
      for (int dblk = 0; dblk < 2; ++dblk) {
        O[(size_t)(n * SEQ + q0 + qt * 32 + qrow) * EMBED + h * HDIM +
          dblk * 32 + l31] = (bf16)(acc[qt][dblk][reg] * rinv);
      }
    }
  }
#undef G_ISSUE
#undef L_WRITE
#undef QK_TILE
#undef EXP_QT
#undef PV_DBLK
#undef ITER
}

// ---------------------------------------------------------------------------
// Kernel 4 (unchanged from R7): LDS-staged out_gemm.
// ---------------------------------------------------------------------------
__global__ __launch_bounds__(256) void out_gemm(
    const bf16* __restrict__ O, const bf16* __restrict__ Wb,
    const float* __restrict__ bo, float* __restrict__ Y) {
  __shared__ __align__(16) char smem[2][2][128 * KVSTRIDE];

  const int tid = threadIdx.x;
  const int lane = tid & 63, wave = tid >> 6;
  const int l31 = lane & 31, hi = lane >> 5;
  const int m0 = blockIdx.x * 128;
  const int j0 = blockIdx.y * 128;
  const int mw = (wave >> 1) * 64, jw = (wave & 1) * 64;

  f16v acc[2][2];
#pragma unroll
  for (int mt = 0; mt < 2; ++mt)
#pragma unroll
    for (int jt = 0; jt < 2; ++jt)
#pragma unroll
      for (int i = 0; i < 16; ++i) acc[mt][jt][i] = 0.f;

  const bf16* Ab = O + (size_t)m0 * EMBED;
  const bf16* Bb = Wb + (size_t)j0 * EMBED;
  const int srow = tid >> 3, seg = tid & 7;
  uint4 ast[4], bst[4];

#define G_ISSUE(kt)                                                            \
  {                                                                            \
    _Pragma("unroll")                                                          \
    for (int rr = 0; rr < 4; ++rr) {                                           \
      ast[rr] = *reinterpret_cast<const uint4*>(                               \
          Ab + (size_t)(srow + 32 * rr) * EMBED + (kt) * 64 + seg * 8);        \
      bst[rr] = *reinterpret_cast<const uint4*>(                               \
          Bb + (size_t)(srow + 32 * rr) * EMBED + (kt) * 64 + seg * 8);        \
    }                                                                          \
  }

#define L_WRITE(c)                                                             \
  {                                                                            \
    _Pragma("unroll")                                                          \
    for (int rr = 0; rr < 4; ++rr) {                                           \
      char* ad = &smem[c][0][(srow + 32 * rr) * KVSTRIDE + seg * 16];          \
      const u64* ap = reinterpret_cast<const u64*>(&ast[rr]);                  \
      *reinterpret_cast<u64*>(ad) = ap[0];                                     \
      *reinterpret_cast<u64*>(ad + 8) = ap[1];                                 \
      char* bd = &smem[c][1][(srow + 32 * rr) * KVSTRIDE + seg * 16];          \
      const u64* bp = reinterpret_cast<const u64*>(&bst[rr]);                  \
      *reinterpret_cast<u64*>(bd) = bp[0];                                     \
      *reinterpret_cast<u64*>(bd + 8) = bp[1];                                 \
    }                                                                          \
  }

  G_ISSUE(0);
  L_WRITE(0);
  __syncthreads();
  int cur = 0;

  for (int kt = 0; kt < EMBED / 64; ++kt) {
    if (kt + 1 < EMBED / 64) G_ISSUE(kt + 1);

    const char* at = smem[cur][0];
    const char* bt = smem[cur][1];

    __builtin_amdgcn_s_setprio(1);
#pragma unroll
    for (int dk = 0; dk < 4; ++dk) {
      b8v a[2], b[2];
#pragma unroll
      for (int mt = 0; mt < 2; ++mt)
        a[mt] = lds_b8(at + (mw + mt * 32 + l31) * KVSTRIDE + dk * 32 + hi * 16);
#pragma unroll
      for (int jt = 0; jt < 2; ++jt)
        b[jt] = lds_b8(bt + (jw + jt * 32 + l31) * KVSTRIDE + dk * 32 + hi * 16);
      acc[0][0] = mfma32(a[0], b[0], acc[0][0]);
      acc[0][1] = mfma32(a[0], b[1], acc[0][1]);
      acc[1][0] = mfma32(a[1], b[0], acc[1][0]);
      acc[1][1] = mfma32(a[1], b[1], acc[1][1]);
    }
    __builtin_amdgcn_s_setprio(0);

    if (kt + 1 < EMBED / 64) L_WRITE(cur ^ 1);
    __syncthreads();
    cur ^= 1;
  }

#pragma unroll
  for (int jt = 0; jt < 2; ++jt) {
    const float bias = bo[j0 + jw + jt * 32 + l31];
#pragma unroll
    for (int mt = 0; mt < 2; ++mt)
#pragma unroll
      for (int reg = 0; reg < 16; ++reg) {
        const int mrow = (reg & 3) + 8 * (reg >> 2) + 4 * hi;
        Y[(size_t)(m0 + mw + mt * 32 + mrow) * EMBED + j0 + jw + jt * 32 + l31] =
            acc[mt][jt][reg] + bias;
      }
  }
#undef G_ISSUE
#undef L_WRITE
}

// ---------------------------------------------------------------------------
extern "C" void kernel_launch(void* const* d_in, const int* in_sizes, int n_in,
                              void* d_out, int out_size, void* d_ws, size_t ws_size,
                              hipStream_t stream) {
  const float* query  = (const float*)d_in[0];
  const float* keys   = (const float*)d_in[1];
  const float* values = (const float*)d_in[2];
  const float* Wq = (const float*)d_in[3];
  const float* Wk = (const float*)d_in[4];
  const float* Wv = (const float*)d_in[5];
  const float* Wo = (const float*)d_in[6];
  const float* bo = (const float*)d_in[7];
  float* Y = (float*)d_out;

  char* ws = (char*)d_ws;
  const size_t szP = (size_t)NBATCH * HEADS * SEQ * HDIM * sizeof(bf16);  // 16.78 MB
  bf16* Qp  = (bf16*)(ws);
  bf16* Kp  = (bf16*)(ws + szP);
  bf16* VpT = (bf16*)(ws + 2 * szP);
  bf16* O   = (bf16*)(ws + 3 * szP);
  bf16* Wb  = (bf16*)(ws + 4 * szP);

  proj_kernel<<<dim3(1024, 4), dim3(256), 0, stream>>>(
      query, keys, values, Wq, Wk, Wv, Wo, Qp, Kp, VpT, Wb);
  attn_kernel<<<dim3(512), dim3(256), 0, stream>>>(Qp, Kp, VpT, O);
  out_gemm<<<dim3(64, 8), dim3(256), 0, stream>>>(O, Wb, bo, Y);
}

// Round 11
// 122.780 us; speedup vs baseline: 4.5882x; 1.4204x over previous
//
#include <hip/hip_runtime.h>

#define EMBED 1024
#define HEADS 16
#define HDIM 64
#define SEQ 2048
#define NBATCH 4
#define KVSTRIDE 136  // 68 bf16: 34 dwords = 2 mod 32 banks -> <=2-way col reads
#define VOFF (64 * KVSTRIDE)
#define NT (SEQ / 64)

typedef __bf16 bf16;
typedef __bf16 b8v __attribute__((ext_vector_type(8)));
typedef __bf16 b4v __attribute__((ext_vector_type(4)));
typedef float f4v __attribute__((ext_vector_type(4)));
typedef float f16v __attribute__((ext_vector_type(16)));
typedef unsigned long long u64;

#define QSCALE 0.045084220027780106f  // log2(e) / sqrt(EMBED)

static __device__ __forceinline__ f16v mfma32(b8v a, b8v b, f16v c) {
  return __builtin_amdgcn_mfma_f32_32x32x16_bf16(a, b, c, 0, 0, 0);
}

static __device__ __forceinline__ b8v lds_b8(const char* p) {
  const b4v lo = *reinterpret_cast<const b4v*>(p);
  const b4v h4 = *reinterpret_cast<const b4v*>(p + 8);
  b8v r;
#pragma unroll
  for (int j = 0; j < 4; ++j) { r[j] = lo[j]; r[4 + j] = h4[j]; }
  return r;
}

// ---------------------------------------------------------------------------
// Kernel 1 (unchanged from R6): fused Q/K/V projection + Wo cvt. grid=(1024,4).
// ---------------------------------------------------------------------------
__global__ __launch_bounds__(256) void proj_kernel(
    const float* __restrict__ q_in, const float* __restrict__ k_in,
    const float* __restrict__ v_in, const float* __restrict__ Wq,
    const float* __restrict__ Wk, const float* __restrict__ Wv,
    const float* __restrict__ Wo, bf16* __restrict__ Qp,
    bf16* __restrict__ Kp, bf16* __restrict__ VpT, bf16* __restrict__ Wb) {
  const int mode = blockIdx.y;
  const int tid = threadIdx.x;

  if (mode == 3) {
    const int i = (blockIdx.x * 256 + tid) * 4;
    const f4v v = *reinterpret_cast<const f4v*>(Wo + i);
    b4v o;
    o[0] = (bf16)v[0]; o[1] = (bf16)v[1]; o[2] = (bf16)v[2]; o[3] = (bf16)v[3];
    *reinterpret_cast<b4v*>(Wb + i) = o;
    return;
  }

  __shared__ __align__(16) char xl[128 * KVSTRIDE];
  __shared__ __align__(16) char wl[64 * KVSTRIDE];
  __shared__ __align__(16) char ol[128 * KVSTRIDE];  // mode2 uses [64][264B]

  const float* x = (mode == 0) ? q_in : (mode == 1) ? k_in : v_in;
  const float* W = (mode == 0) ? Wq : (mode == 1) ? Wk : Wv;
  const float wscale = (mode == 0) ? QSCALE : 1.0f;

  const int lane = tid & 63, wave = tid >> 6;
  const int l31 = lane & 31, hi = lane >> 5;
  const int bid = blockIdx.x;
  const int stile = bid & 15, nh = bid >> 4;
  const int n = nh >> 4, h = nh & 15;
  const int s0 = stile * 128;

  const float* xb = x + (size_t)(n * SEQ + s0) * EMBED + h * HDIM;
#pragma unroll
  for (int r = 0; r < 8; ++r) {
    const int idx = r * 256 + tid;
    const int row = idx >> 4, c = idx & 15;
    const f4v v = *reinterpret_cast<const f4v*>(xb + (size_t)row * EMBED + c * 4);
    b4v o;
    o[0] = (bf16)v[0]; o[1] = (bf16)v[1]; o[2] = (bf16)v[2]; o[3] = (bf16)v[3];
    *reinterpret_cast<b4v*>(xl + row * KVSTRIDE + c * 8) = o;
  }
#pragma unroll
  for (int r = 0; r < 4; ++r) {
    const int idx = r * 256 + tid;
    const int row = idx >> 4, c = idx & 15;
    const f4v v = *reinterpret_cast<const f4v*>(W + row * 64 + c * 4);
    b4v o;
    o[0] = (bf16)(v[0] * wscale); o[1] = (bf16)(v[1] * wscale);
    o[2] = (bf16)(v[2] * wscale); o[3] = (bf16)(v[3] * wscale);
    *reinterpret_cast<b4v*>(wl + row * KVSTRIDE + c * 8) = o;
  }
  __syncthreads();

  const int s0w = wave * 32;
  b8v wf[2][4], xf[4];
#pragma unroll
  for (int eb = 0; eb < 2; ++eb)
#pragma unroll
    for (int dk = 0; dk < 4; ++dk)
      wf[eb][dk] = lds_b8(wl + (eb * 32 + l31) * KVSTRIDE + dk * 32 + hi * 16);
#pragma unroll
  for (int dk = 0; dk < 4; ++dk)
    xf[dk] = lds_b8(xl + (s0w + l31) * KVSTRIDE + dk * 32 + hi * 16);

  if (mode < 2) {
#pragma unroll
    for (int eb = 0; eb < 2; ++eb) {
      f16v d;
#pragma unroll
      for (int i = 0; i < 16; ++i) d[i] = 0.f;
#pragma unroll
      for (int dk = 0; dk < 4; ++dk) d = mfma32(wf[eb][dk], xf[dk], d);
      char* orow = ol + (s0w + l31) * KVSTRIDE + eb * 64 + hi * 8;
#pragma unroll
      for (int qd = 0; qd < 4; ++qd) {
        b4v o;
#pragma unroll
        for (int rr = 0; rr < 4; ++rr) o[rr] = (bf16)d[qd * 4 + rr];
        *reinterpret_cast<b4v*>(orow + qd * 16) = o;
      }
    }
  } else {
#pragma unroll
    for (int eb = 0; eb < 2; ++eb) {
      f16v d;
#pragma unroll
      for (int i = 0; i < 16; ++i) d[i] = 0.f;
#pragma unroll
      for (int dk = 0; dk < 4; ++dk) d = mfma32(xf[dk], wf[eb][dk], d);
      char* orow = ol + (eb * 32 + l31) * 264 + s0w * 2 + hi * 8;
#pragma unroll
      for (int qd = 0; qd < 4; ++qd) {
        b4v o;
#pragma unroll
        for (int rr = 0; rr < 4; ++rr) o[rr] = (bf16)d[qd * 4 + rr];
        *reinterpret_cast<b4v*>(orow + qd * 16) = o;
      }
    }
  }
  __syncthreads();

  if (mode < 2) {
    bf16* outb = ((mode == 0) ? Qp : Kp) + (size_t)nh * SEQ * HDIM +
                 (size_t)s0 * HDIM;
#pragma unroll
    for (int r = 0; r < 4; ++r) {
      const int idx = r * 256 + tid;
      const int row = idx >> 3, c8 = idx & 7;
      const u64 a = *reinterpret_cast<const u64*>(ol + row * KVSTRIDE + c8 * 16);
      const u64 b = *reinterpret_cast<const u64*>(ol + row * KVSTRIDE + c8 * 16 + 8);
      uint4 v;
      v.x = (unsigned)a; v.y = (unsigned)(a >> 32);
      v.z = (unsigned)b; v.w = (unsigned)(b >> 32);
      *reinterpret_cast<uint4*>(outb + (size_t)row * HDIM + c8 * 8) = v;
    }
  } else {
    bf16* outb = VpT + (size_t)nh * HDIM * SEQ + s0;
#pragma unroll
    for (int r = 0; r < 4; ++r) {
      const int idx = r * 256 + tid;
      const int row = idx >> 4, c = idx & 15;
      const u64 a = *reinterpret_cast<const u64*>(ol + row * 264 + c * 16);
      const u64 b = *reinterpret_cast<const u64*>(ol + row * 264 + c * 16 + 8);
      uint4 v;
      v.x = (unsigned)a; v.y = (unsigned)(a >> 32);
      v.z = (unsigned)b; v.w = (unsigned)(b >> 32);
      *reinterpret_cast<uint4*>(outb + (size_t)row * SEQ + c * 8) = v;
    }
  }
}

// ---------------------------------------------------------------------------
// Kernel 2: EXACT R8 pipelined flash attn (best measured: 75 us, no spill).
// Per iter: QK(t+1) -> [PV(t) MFMA || softmax(t+1) VALU] -> stage(t+2) ->
// barrier. 3-buffer LDS rotation (runtime pointer swap), per-iter S zero-init,
// 32-mov pa handoff — proven codegen, do not "optimize" (R9/R10 both spilled).
// ---------------------------------------------------------------------------
__global__ __launch_bounds__(256, 2) void attn_kernel(
    const bf16* __restrict__ Qp, const bf16* __restrict__ Kp,
    const bf16* __restrict__ VpT, bf16* __restrict__ O) {
  __shared__ __align__(16) char smem[3][2 * 64 * KVSTRIDE];  // [buf][K | V]

  const int tid = threadIdx.x;
  const int lane = tid & 63, wave = tid >> 6;
  const int l31 = lane & 31, hi = lane >> 5;

  const int bid = blockIdx.x;
  const int nh = bid & 63, qb = bid >> 6;  // nh-major -> per-head XCD locality
  const int n = nh >> 4, h = nh & 15;
  const int q0 = qb * 256 + wave * 64;

  const bf16* Qnh = Qp + (size_t)nh * SEQ * HDIM;
  const bf16* Knh = Kp + (size_t)nh * SEQ * HDIM;
  const bf16* Vnh = VpT + (size_t)nh * HDIM * SEQ;

  // Q B-fragments (q = q0 + qt*32 + l31), pre-scaled by log2e/32.
  b8v bq[2][4];
#pragma unroll
  for (int qt = 0; qt < 2; ++qt)
#pragma unroll
    for (int dk = 0; dk < 4; ++dk)
      bq[qt][dk] = *reinterpret_cast<const b8v*>(
          Qnh + (size_t)(q0 + qt * 32 + l31) * HDIM + dk * 16 + hi * 8);

  f16v acc[2][2];
#pragma unroll
  for (int qt = 0; qt < 2; ++qt)
#pragma unroll
    for (int dblk = 0; dblk < 2; ++dblk)
#pragma unroll
      for (int i = 0; i < 16; ++i) acc[qt][dblk][i] = 0.f;
  float lsum0 = 0.f, lsum1 = 0.f;

  const int srow = tid >> 3, seg = tid & 7;
  uint4 kst[2], vst[2];

#define G_ISSUE(kv0)                                                           \
  {                                                                            \
    kst[0] = *reinterpret_cast<const uint4*>(Knh + (size_t)((kv0) + srow) * HDIM + seg * 8); \
    kst[1] = *reinterpret_cast<const uint4*>(Knh + (size_t)((kv0) + srow + 32) * HDIM + seg * 8); \
    vst[0] = *reinterpret_cast<const uint4*>(Vnh + (size_t)srow * SEQ + (kv0) + seg * 8); \
    vst[1] = *reinterpret_cast<const uint4*>(Vnh + (size_t)(srow + 32) * SEQ + (kv0) + seg * 8); \
  }

#define L_WRITE(base)                                                          \
  {                                                                            \
    _Pragma("unroll")                                                          \
    for (int rr = 0; rr < 2; ++rr) {                                           \
      char* kd = (base) + (srow + 32 * rr) * KVSTRIDE + seg * 16;              \
      const u64* kp = reinterpret_cast<const u64*>(&kst[rr]);                  \
      *reinterpret_cast<u64*>(kd) = kp[0];                                     \
      *reinterpret_cast<u64*>(kd + 8) = kp[1];                                 \
      char* vd = (base) + VOFF + (srow + 32 * rr) * KVSTRIDE + seg * 16;       \
      const u64* vp = reinterpret_cast<const u64*>(&vst[rr]);                  \
      *reinterpret_cast<u64*>(vd) = vp[0];                                     \
      *reinterpret_cast<u64*>(vd + 8) = vp[1];                                 \
    }                                                                          \
  }

// QK of one tile from K at kbase -> s[2][2] ([qt][g], f16v each)
#define QK_TILE(kbase, s)                                                      \
  {                                                                            \
    _Pragma("unroll")                                                          \
    for (int g = 0; g < 2; ++g) {                                              \
      _Pragma("unroll")                                                        \
      for (int i = 0; i < 16; ++i) { s[0][g][i] = 0.f; s[1][g][i] = 0.f; }     \
      const char* kr = (kbase) + (g * 32 + l31) * KVSTRIDE + hi * 16;          \
      _Pragma("unroll")                                                        \
      for (int dk = 0; dk < 4; ++dk) {                                         \
        const b8v ak = lds_b8(kr + dk * 32);                                   \
        s[0][g] = mfma32(ak, bq[0][dk], s[0][g]);                              \
        s[1][g] = mfma32(ak, bq[1][dk], s[1][g]);                              \
      }                                                                        \
    }                                                                          \
  }

// softmax of one qt: pa[2][2] from s[2] (both g), accumulate psum
#define EXP_QT(sg0, sg1, pa, psum)                                             \
  {                                                                            \
    _Pragma("unroll")                                                          \
    for (int reg = 0; reg < 16; ++reg) {                                       \
      const float p0 = __builtin_amdgcn_exp2f(sg0[reg]);                       \
      const float p1 = __builtin_amdgcn_exp2f(sg1[reg]);                       \
      psum += p0 + p1;                                                         \
      pa[0][reg >> 3][reg & 7] = (bf16)p0;                                     \
      pa[1][reg >> 3][reg & 7] = (bf16)p1;                                     \
    }                                                                          \
  }

// PV of one dblk for tile at vbase using pa frags
#define PV_DBLK(vbase, dblk, paA, paB)                                         \
  {                                                                            \
    const char* vr = (vbase) + VOFF + ((dblk) * 32 + l31) * KVSTRIDE + hi * 8; \
    _Pragma("unroll")                                                          \
    for (int g = 0; g < 2; ++g) {                                              \
      _Pragma("unroll")                                                        \
      for (int kc = 0; kc < 2; ++kc) {                                         \
        const b4v lo = *reinterpret_cast<const b4v*>(vr + g * 64 + kc * 32);   \
        const b4v h4 = *reinterpret_cast<const b4v*>(vr + g * 64 + kc * 32 + 16); \
        b8v bv;                                                                \
        _Pragma("unroll")                                                      \
        for (int j = 0; j < 4; ++j) { bv[j] = lo[j]; bv[4 + j] = h4[j]; }      \
        acc[0][dblk] = mfma32(paA[g][kc], bv, acc[0][dblk]);                   \
        acc[1][dblk] = mfma32(paB[g][kc], bv, acc[1][dblk]);                   \
      }                                                                        \
    }                                                                          \
  }

  // ---- prologue: stage tiles 0,1; QK(0)+softmax(0) ----
  G_ISSUE(0);
  L_WRITE(smem[0]);
  G_ISSUE(64);
  L_WRITE(smem[1]);
  __syncthreads();

  char* pC = smem[0];  // tile t
  char* pN = smem[1];  // tile t+1
  char* pF = smem[2];  // target for tile t+2

  b8v paP[2][2][2];  // [qt][g][kc] current tile's P
  {
    f16v s[2][2];
    QK_TILE(pC, s);
    float ps0 = 0.f, ps1 = 0.f;
    EXP_QT(s[0][0], s[0][1], paP[0], ps0);
    EXP_QT(s[1][0], s[1][1], paP[1], ps1);
    lsum0 += ps0;
    lsum1 += ps1;
  }

  // ---- main loop: t = 0..NT-2 ----
  for (int t = 0; t < NT - 1; ++t) {
    const bool more = (t + 2 < NT);
    if (more) G_ISSUE((t + 2) * 64);

    // QK(t+1) from pN
    f16v s[2][2];
    __builtin_amdgcn_s_setprio(1);
    QK_TILE(pN, s);
    __builtin_amdgcn_s_setprio(0);

    // PV(t) (MFMA, uses paP + V at pC) || softmax(t+1) (VALU, uses s) —
    // independent streams; interleaved at source chunk level.
    b8v paN[2][2][2];
    float ps0 = 0.f, ps1 = 0.f;
    PV_DBLK(pC, 0, paP[0], paP[1]);
    EXP_QT(s[0][0], s[0][1], paN[0], ps0);
    PV_DBLK(pC, 1, paP[0], paP[1]);
    EXP_QT(s[1][0], s[1][1], paN[1], ps1);
    lsum0 += ps0;
    lsum1 += ps1;

    if (more) L_WRITE(pF);

    // hand over: paP <- paN, rotate buffers
#pragma unroll
    for (int qt = 0; qt < 2; ++qt)
#pragma unroll
      for (int g = 0; g < 2; ++g)
#pragma unroll
        for (int kc = 0; kc < 2; ++kc) paP[qt][g][kc] = paN[qt][g][kc];
    char* tmp = pC; pC = pN; pN = pF; pF = tmp;
    __syncthreads();
  }

  // ---- epilogue: PV(NT-1) ----
  __builtin_amdgcn_s_setprio(1);
  PV_DBLK(pC, 0, paP[0], paP[1]);
  PV_DBLK(pC, 1, paP[0], paP[1]);
  __builtin_amdgcn_s_setprio(0);

  lsum0 += __shfl_xor(lsum0, 32);
  lsum1 += __shfl_xor(lsum1, 32);

#pragma unroll
  for (int qt = 0; qt < 2; ++qt) {
    const float ls = (qt == 0) ? lsum0 : lsum1;
#pragma unroll
    for (int reg = 0; reg < 16; ++reg) {
      const int qrow = (reg & 3) + 8 * (reg >> 2) + 4 * hi;
      const float rinv = __builtin_amdgcn_rcpf(__shfl(ls, qrow, 64));
#pragma unroll
      for (int dblk = 0; dblk < 2; ++dblk) {
        O[(size_t)(n * SEQ + q0 + qt * 32 + qrow) * EMBED + h * HDIM +
          dblk * 32 + l31] = (bf16)(acc[qt][dblk][reg] * rinv);
      }
    }
  }
#undef G_ISSUE
#undef L_WRITE
#undef QK_TILE
#undef EXP_QT
#undef PV_DBLK
}

// ---------------------------------------------------------------------------
// Kernel 4 (unchanged from R7): LDS-staged out_gemm.
// ---------------------------------------------------------------------------
__global__ __launch_bounds__(256) void out_gemm(
    const bf16* __restrict__ O, const bf16* __restrict__ Wb,
    const float* __restrict__ bo, float* __restrict__ Y) {
  __shared__ __align__(16) char smem[2][2][128 * KVSTRIDE];

  const int tid = threadIdx.x;
  const int lane = tid & 63, wave = tid >> 6;
  const int l31 = lane & 31, hi = lane >> 5;
  const int m0 = blockIdx.x * 128;
  const int j0 = blockIdx.y * 128;
  const int mw = (wave >> 1) * 64, jw = (wave & 1) * 64;

  f16v acc[2][2];
#pragma unroll
  for (int mt = 0; mt < 2; ++mt)
#pragma unroll
    for (int jt = 0; jt < 2; ++jt)
#pragma unroll
      for (int i = 0; i < 16; ++i) acc[mt][jt][i] = 0.f;

  const bf16* Ab = O + (size_t)m0 * EMBED;
  const bf16* Bb = Wb + (size_t)j0 * EMBED;
  const int srow = tid >> 3, seg = tid & 7;
  uint4 ast[4], bst[4];

#define G_ISSUE(kt)                                                            \
  {                                                                            \
    _Pragma("unroll")                                                          \
    for (int rr = 0; rr < 4; ++rr) {                                           \
      ast[rr] = *reinterpret_cast<const uint4*>(                               \
          Ab + (size_t)(srow + 32 * rr) * EMBED + (kt) * 64 + seg * 8);        \
      bst[rr] = *reinterpret_cast<const uint4*>(                               \
          Bb + (size_t)(srow + 32 * rr) * EMBED + (kt) * 64 + seg * 8);        \
    }                                                                          \
  }

#define L_WRITE(c)                                                             \
  {                                                                            \
    _Pragma("unroll")                                                          \
    for (int rr = 0; rr < 4; ++rr) {                                           \
      char* ad = &smem[c][0][(srow + 32 * rr) * KVSTRIDE + seg * 16];          \
      const u64* ap = reinterpret_cast<const u64*>(&ast[rr]);                  \
      *reinterpret_cast<u64*>(ad) = ap[0];                                     \
      *reinterpret_cast<u64*>(ad + 8) = ap[1];                                 \
      char* bd = &smem[c][1][(srow + 32 * rr) * KVSTRIDE + seg * 16];          \
      const u64* bp = reinterpret_cast<const u64*>(&bst[rr]);                  \
      *reinterpret_cast<u64*>(bd) = bp[0];                                     \
      *reinterpret_cast<u64*>(bd + 8) = bp[1];                                 \
    }                                                                          \
  }

  G_ISSUE(0);
  L_WRITE(0);
  __syncthreads();
  int cur = 0;

  for (int kt = 0; kt < EMBED / 64; ++kt) {
    if (kt + 1 < EMBED / 64) G_ISSUE(kt + 1);

    const char* at = smem[cur][0];
    const char* bt = smem[cur][1];

    __builtin_amdgcn_s_setprio(1);
#pragma unroll
    for (int dk = 0; dk < 4; ++dk) {
      b8v a[2], b[2];
#pragma unroll
      for (int mt = 0; mt < 2; ++mt)
        a[mt] = lds_b8(at + (mw + mt * 32 + l31) * KVSTRIDE + dk * 32 + hi * 16);
#pragma unroll
      for (int jt = 0; jt < 2; ++jt)
        b[jt] = lds_b8(bt + (jw + jt * 32 + l31) * KVSTRIDE + dk * 32 + hi * 16);
      acc[0][0] = mfma32(a[0], b[0], acc[0][0]);
      acc[0][1] = mfma32(a[0], b[1], acc[0][1]);
      acc[1][0] = mfma32(a[1], b[0], acc[1][0]);
      acc[1][1] = mfma32(a[1], b[1], acc[1][1]);
    }
    __builtin_amdgcn_s_setprio(0);

    if (kt + 1 < EMBED / 64) L_WRITE(cur ^ 1);
    __syncthreads();
    cur ^= 1;
  }

#pragma unroll
  for (int jt = 0; jt < 2; ++jt) {
    const float bias = bo[j0 + jw + jt * 32 + l31];
#pragma unroll
    for (int mt = 0; mt < 2; ++mt)
#pragma unroll
      for (int reg = 0; reg < 16; ++reg) {
        const int mrow = (reg & 3) + 8 * (reg >> 2) + 4 * hi;
        Y[(size_t)(m0 + mw + mt * 32 + mrow) * EMBED + j0 + jw + jt * 32 + l31] =
            acc[mt][jt][reg] + bias;
      }
  }
#undef G_ISSUE
#undef L_WRITE
}

// ---------------------------------------------------------------------------
extern "C" void kernel_launch(void* const* d_in, const int* in_sizes, int n_in,
                              void* d_out, int out_size, void* d_ws, size_t ws_size,
                              hipStream_t stream) {
  const float* query  = (const float*)d_in[0];
  const float* keys   = (const float*)d_in[1];
  const float* values = (const float*)d_in[2];
  const float* Wq = (const float*)d_in[3];
  const float* Wk = (const float*)d_in[4];
  const float* Wv = (const float*)d_in[5];
  const float* Wo = (const float*)d_in[6];
  const float* bo = (const float*)d_in[7];
  float* Y = (float*)d_out;

  char* ws = (char*)d_ws;
  const size_t szP = (size_t)NBATCH * HEADS * SEQ * HDIM * sizeof(bf16);  // 16.78 MB
  bf16* Qp  = (bf16*)(ws);
  bf16* Kp  = (bf16*)(ws + szP);
  bf16* VpT = (bf16*)(ws + 2 * szP);
  bf16* O   = (bf16*)(ws + 3 * szP);
  bf16* Wb  = (bf16*)(ws + 4 * szP);

  proj_kernel<<<dim3(1024, 4), dim3(256), 0, stream>>>(
      query, keys, values, Wq, Wk, Wv, Wo, Qp, Kp, VpT, Wb);
  attn_kernel<<<dim3(512), dim3(256), 0, stream>>>(Qp, Kp, VpT, O);
  out_gemm<<<dim3(64, 8), dim3(256), 0, stream>>>(O, Wb, bo, Y);
}